// Round 7
// baseline (299.095 us; speedup 1.0000x reference)
//
#include <hip/hip_runtime.h>

#define N_POS 4096
#define NJ 4094     // N-2 valid sign-change positions
#define RPB 8       // rows per count-block

typedef float f32x4 __attribute__((ext_vector_type(4)));  // nt-store-compatible
typedef unsigned long long ull;

// ---------------------------------------------------------------------------
// Kernel 1: count peaks/valleys of the second difference.
// Grid: (2 position-chunks of 2048, rows/RPB = 1024) = 2048 blocks, block 256.
// Each thread owns 8 consecutive positions: 3 loads/row (2x float4 + float2,
// 40 B fetched for 32 B useful) register-staged in two 4-row batches
// (~10 KB in flight per wave). Halo branch-free: the single tail thread
// (j0 == 4088) re-reads its own row start; those values only feed positions
// >= NJ whose atomics are guarded off. Two adjacent positions packed per
// 64-bit atomicAdd (pk low16 | vl high16 per 32-bit half; NJ even ->
// pairs never straddle validity).
// ---------------------------------------------------------------------------
__global__ __launch_bounds__(256) void count_kernel(
    const float* __restrict__ x,
    ull* __restrict__ cnt64)
{
    const int tid = threadIdx.x;
    const int j0  = blockIdx.x * 2048 + tid * 8;
    const size_t row0 = (size_t)blockIdx.y * RPB;

    const float* base = x + row0 * N_POS + j0;
    const bool tail = (j0 + 8 >= N_POS);   // only j0 == 4088
    const int halo_off = tail ? 0 : 8;     // tail reads in-bounds garbage

    unsigned int pk[8] = {0,0,0,0,0,0,0,0};
    unsigned int vl[8] = {0,0,0,0,0,0,0,0};

    #pragma unroll
    for (int h = 0; h < RPB / 4; ++h) {
        float4 A0[4], A1[4];
        float2 B[4];
        const float* hb = base + (size_t)(h * 4) * N_POS;
        #pragma unroll
        for (int r = 0; r < 4; ++r) {
            const float* rowp = hb + (size_t)r * N_POS;
            A0[r] = *reinterpret_cast<const float4*>(rowp);
            A1[r] = *reinterpret_cast<const float4*>(rowp + 4);
            B[r]  = *reinterpret_cast<const float2*>(rowp + halo_off);
        }
        #pragma unroll
        for (int r = 0; r < 4; ++r) {
            float e[10];
            e[0] = A0[r].x; e[1] = A0[r].y; e[2] = A0[r].z; e[3] = A0[r].w;
            e[4] = A1[r].x; e[5] = A1[r].y; e[6] = A1[r].z; e[7] = A1[r].w;
            e[8] = B[r].x;  e[9] = B[r].y;
            #pragma unroll
            for (int k = 0; k < 8; ++k) {
                float s = (e[k + 2] - e[k + 1]) - (e[k + 1] - e[k]);
                pk[k] += (s < 0.f);
                vl[k] += (s > 0.f);
            }
        }
    }

    #pragma unroll
    for (int k = 0; k < 8; k += 2) {
        if (j0 + k < NJ) {   // pair base even, NJ even -> all-or-nothing
            ull lo = (ull)(pk[k]     | (vl[k]     << 16));
            ull hi = (ull)(pk[k + 1] | (vl[k + 1] << 16));
            atomicAdd(&cnt64[(j0 + k) >> 1], lo | (hi << 32));
        }
    }
}

// ---------------------------------------------------------------------------
// Kernel 2: vec + global min/max. 16 blocks x 256 threads, one position per
// thread. Counts staged in LDS with +/-130 halo; Gaussian weight tables in
// LDS (truncated at radius ceil(8w)+1 <= 128; dropped terms < e^-64,
// negligible vs the 2e-2 absmax threshold on a [0,1]-normalized output).
// Min/max via monotonic-uint atomicMax (vec >= 0): mm[0] holds
// max(0x7FFFFFFF - bits(v)) -> decodes to min; mm[1] holds max(bits(v)).
// Both init to 0 by the same memset that zeroes cnt.
// ---------------------------------------------------------------------------
__global__ __launch_bounds__(256) void vec_kernel(
    const unsigned int* __restrict__ cnt,
    const float* __restrict__ log_pw,
    const float* __restrict__ log_vw,
    float* __restrict__ vec,
    unsigned int* __restrict__ mm)
{
    __shared__ float s_pk[520];
    __shared__ float s_vl[520];
    __shared__ float s_gp[257];   // weights for dist in [-128, 128]
    __shared__ float s_gv[257];
    __shared__ float smn[4], smx[4];

    const int tid = threadIdx.x;
    const int jb  = blockIdx.x * 256 - 130;

    const float wp = __expf(log_pw[0]);
    const float wv = __expf(log_vw[0]);
    const float ip2 = 1.f / (wp * wp);
    const float iv2 = 1.f / (wv * wv);
    const int Rp = min(128, (int)ceilf(wp * 8.f) + 1);
    const int Rv = min(128, (int)ceilf(wv * 8.f) + 1);

    for (int i = tid; i < 520; i += 256) {
        int j = jb + i;
        unsigned int c = (j >= 0 && j < NJ) ? cnt[j] : 0u;
        s_pk[i] = (float)(c & 0xFFFFu);
        s_vl[i] = (float)(c >> 16);
    }
    for (int i = tid; i < 257; i += 256) {
        float dd = (float)(i - 128);
        s_gp[i] = __expf(-dd * dd * ip2);
        s_gv[i] = __expf(-dd * dd * iv2);
    }
    __syncthreads();

    const int p = blockIdx.x * 256 + tid;
    float sum = 0.f;
    {   // peaks: centers c = j+1 in [1, NJ]
        int clo = max(1, p - Rp), chi = min(NJ, p + Rp);
        for (int c = clo; c <= chi; ++c)
            sum += s_pk[c - 1 - jb] * s_gp[p - c + 128];
    }
    {   // valleys
        int clo = max(1, p - Rv), chi = min(NJ, p + Rv);
        for (int c = clo; c <= chi; ++c)
            sum += s_vl[c - 1 - jb] * s_gv[p - c + 128];
    }
    vec[p] = sum;

    float mn = sum, mx = sum;
    for (int off = 32; off; off >>= 1) {
        mn = fminf(mn, __shfl_down(mn, off));
        mx = fmaxf(mx, __shfl_down(mx, off));
    }
    if ((tid & 63) == 0) { smn[tid >> 6] = mn; smx[tid >> 6] = mx; }
    __syncthreads();
    if (tid == 0) {
        mn = fminf(fminf(smn[0], smn[1]), fminf(smn[2], smn[3]));
        mx = fmaxf(fmaxf(smx[0], smx[1]), fmaxf(smx[2], smx[3]));
        atomicMax(&mm[0], 0x7FFFFFFFu - __float_as_uint(mn));  // min key
        atomicMax(&mm[1], __float_as_uint(mx));                // max key
    }
}

// ---------------------------------------------------------------------------
// Kernel 3: broadcast + normalize. vec (16 KiB) is L1/L2-resident; write-
// bound at ~134 MB. Nontemporal stores (via native ext_vector_type) skip L2
// write-allocate. Normalization fused (4 FMAs per float4 store, free
// against the write BW).
// ---------------------------------------------------------------------------
__global__ __launch_bounds__(256) void bcast_kernel(
    const float4* __restrict__ vec4,
    const unsigned int* __restrict__ mm,
    f32x4* __restrict__ out4, int total4)
{
    const float mn  = __uint_as_float(0x7FFFFFFFu - mm[0]);
    const float mx  = __uint_as_float(mm[1]);
    const float inv = 1.f / (mx - mn + 1e-6f);

    int idx    = blockIdx.x * blockDim.x + threadIdx.x;
    int stride = gridDim.x * blockDim.x;
    for (int i = idx; i < total4; i += stride) {
        float4 v = vec4[i & 1023];   // N/4 = 1024 (power of two)
        f32x4 o;
        o.x = (v.x - mn) * inv;
        o.y = (v.y - mn) * inv;
        o.z = (v.z - mn) * inv;
        o.w = (v.w - mn) * inv;
        __builtin_nontemporal_store(o, &out4[i]);
    }
}

extern "C" void kernel_launch(void* const* d_in, const int* in_sizes, int n_in,
                              void* d_out, int out_size, void* d_ws, size_t ws_size,
                              hipStream_t stream) {
    const float* x   = (const float*)d_in[0];
    const float* lpw = (const float*)d_in[1];
    const float* lvw = (const float*)d_in[2];

    ull* cnt64 = (ull*)d_ws;                      // 2048 u64 = 4096 packed u32
    unsigned int* cnt = (unsigned int*)d_ws;      // u32 view (little-endian)
    unsigned int* mm  = cnt + 4096;               // [4096..4097] min/max keys
    float* vec = (float*)d_ws + 4352;             // 16-byte aligned

    const int rows = in_sizes[0] / N_POS;         // 8192

    // one memset zeroes counters AND the two minmax keys
    (void)hipMemsetAsync(cnt, 0, (4096 + 2) * sizeof(unsigned int), stream);

    dim3 g1(2, rows / RPB);
    count_kernel<<<g1, 256, 0, stream>>>(x, cnt64);
    vec_kernel<<<16, 256, 0, stream>>>(cnt, lpw, lvw, vec, mm);
    bcast_kernel<<<2048, 256, 0, stream>>>((const float4*)vec, mm,
                                           (f32x4*)d_out, out_size / 4);
}

// Round 8
// 249.385 us; speedup vs baseline: 1.1993x; 1.1993x over previous
//
#include <hip/hip_runtime.h>

#define N_POS 4096
#define NJ 4094     // N-2 valid sign-change positions
#define G 128       // row-groups (partial-count slices)
#define RPB 64      // rows per count-block = 8192 / G

typedef float f32x4 __attribute__((ext_vector_type(4)));  // nt-store-compatible

// ---------------------------------------------------------------------------
// Kernel 1: partial peak/valley counts — ZERO atomics.
// Grid: (4 position-chunks of 1024, G=128 row-groups) = 512 blocks, block 256.
// Each thread owns 4 consecutive positions; float4 + overlapping float2 loads
// register-staged in 8-row batches (~12 KB in flight per wave). Each block
// writes its packed counts (pk | vl<<16) to its OWN slice partial[by][4096]
// with one uint4 store per thread — no contention, no RMW. Garbage counts at
// j >= NJ (from the tail thread's clamped halo) are masked in kernel 2.
// Block (0,0) also zeroes the two min/max keys (replaces the memset launch).
// ---------------------------------------------------------------------------
__global__ __launch_bounds__(256) void partial_kernel(
    const float* __restrict__ x,
    unsigned int* __restrict__ partial,
    unsigned int* __restrict__ mm)
{
    const int tid = threadIdx.x;
    const int j0  = blockIdx.x * 1024 + tid * 4;
    const size_t row0 = (size_t)blockIdx.y * RPB;

    if (blockIdx.x == 0 && blockIdx.y == 0 && tid == 0) {
        mm[0] = 0u;   // min key (atomicMax target in vec_kernel)
        mm[1] = 0u;   // max key
    }

    const float* base = x + row0 * N_POS + j0;
    const bool tail = (j0 + 4 >= N_POS);     // only j0 == 4092
    const int halo_off = tail ? -2 : 4;      // tail reads in-bounds garbage

    unsigned int pk0 = 0, pk1 = 0, pk2 = 0, pk3 = 0;
    unsigned int vl0 = 0, vl1 = 0, vl2 = 0, vl3 = 0;

    for (int h = 0; h < RPB / 8; ++h) {
        float4 A[8];
        float2 B[8];
        const float* hb = base + (size_t)h * 8 * N_POS;
        #pragma unroll
        for (int r = 0; r < 8; ++r) {
            const float* rowp = hb + (size_t)r * N_POS;
            A[r] = *reinterpret_cast<const float4*>(rowp);
            B[r] = *reinterpret_cast<const float2*>(rowp + halo_off);
        }
        #pragma unroll
        for (int r = 0; r < 8; ++r) {
            const float4 a = A[r];
            const float n0 = B[r].x, n1 = B[r].y;
            float s;
            s = (a.z - a.y) - (a.y - a.x);
            pk0 += (s < 0.f); vl0 += (s > 0.f);
            s = (a.w - a.z) - (a.z - a.y);
            pk1 += (s < 0.f); vl1 += (s > 0.f);
            s = (n0 - a.w) - (a.w - a.z);
            pk2 += (s < 0.f); vl2 += (s > 0.f);
            s = (n1 - n0) - (n0 - a.w);
            pk3 += (s < 0.f); vl3 += (s > 0.f);
        }
    }

    uint4 o;
    o.x = pk0 | (vl0 << 16);
    o.y = pk1 | (vl1 << 16);
    o.z = pk2 | (vl2 << 16);
    o.w = pk3 | (vl3 << 16);
    *reinterpret_cast<uint4*>(&partial[(size_t)blockIdx.y * N_POS + j0]) = o;
}

// ---------------------------------------------------------------------------
// Kernel 2: group-sum + vec + global min/max. 16 blocks x 1024 threads.
// Phase 1: task (q = tid>>3, sub = tid&7) sums G/8 = 16 uint4 partial
// columns for quad q of the 512-wide halo window (jb = bx*256-128, quad-
// aligned). Phase 2: tid<128 combines 8 sub-sums, unpacks with NJ mask into
// s_pk/s_vl. Phase 3: tid<256 does the Gaussian conv (radius clamped to 124;
// for w=3, R=25; dropped terms < e^-64, negligible vs the 2e-2 threshold).
// Min/max via monotonic-uint atomicMax on mm (vec >= 0): mm[0] holds
// max(0x7FFFFFFF - bits(v)) -> min; mm[1] holds max(bits(v)).
// ---------------------------------------------------------------------------
__global__ __launch_bounds__(1024) void vec_kernel(
    const unsigned int* __restrict__ partial,
    const float* __restrict__ log_pw,
    const float* __restrict__ log_vw,
    float* __restrict__ vec,
    unsigned int* __restrict__ mm)
{
    __shared__ uint4  s_red[128][8];
    __shared__ float  s_pk[512], s_vl[512];
    __shared__ float  s_gp[256], s_gv[256];   // dist = idx - 128
    __shared__ float  smn[4], smx[4];

    const int tid = threadIdx.x;
    const int jb  = blockIdx.x * 256 - 128;   // quad-aligned window base

    // Phase 1: partial group-sums (all 1024 threads)
    {
        const int q = tid >> 3, sub = tid & 7;
        const int jq = jb + q * 4;
        uint4 acc; acc.x = acc.y = acc.z = acc.w = 0;
        if (jq >= 0 && jq + 3 < N_POS) {
            const unsigned int* colp = partial + (size_t)(sub * (G / 8)) * N_POS + jq;
            #pragma unroll 4
            for (int g = 0; g < G / 8; ++g) {
                uint4 v = *reinterpret_cast<const uint4*>(colp + (size_t)g * N_POS);
                acc.x += v.x; acc.y += v.y; acc.z += v.z; acc.w += v.w;
            }
        }
        s_red[q][sub] = acc;
    }

    // Gaussian tables (threads 0..255)
    const float wp = __expf(log_pw[0]);
    const float wv = __expf(log_vw[0]);
    const float ip2 = 1.f / (wp * wp);
    const float iv2 = 1.f / (wv * wv);
    const int Rp = min(124, (int)ceilf(wp * 8.f) + 1);
    const int Rv = min(124, (int)ceilf(wv * 8.f) + 1);
    if (tid < 256) {
        float dd = (float)(tid - 128);
        s_gp[tid] = __expf(-dd * dd * ip2);
        s_gv[tid] = __expf(-dd * dd * iv2);
    }
    __syncthreads();

    // Phase 2: combine 8 sub-sums, unpack with NJ mask
    if (tid < 128) {
        uint4 a; a.x = a.y = a.z = a.w = 0;
        #pragma unroll
        for (int s = 0; s < 8; ++s) {
            uint4 v = s_red[tid][s];
            a.x += v.x; a.y += v.y; a.z += v.z; a.w += v.w;
        }
        const int jq = jb + tid * 4;
        unsigned int e[4] = {a.x, a.y, a.z, a.w};
        #pragma unroll
        for (int k = 0; k < 4; ++k) {
            int j = jq + k;
            unsigned int c = (j >= 0 && j < NJ) ? e[k] : 0u;
            s_pk[tid * 4 + k] = (float)(c & 0xFFFFu);
            s_vl[tid * 4 + k] = (float)(c >> 16);
        }
    }
    __syncthreads();

    // Phase 3: convolution + min/max (threads 0..255)
    if (tid < 256) {
        const int p = blockIdx.x * 256 + tid;
        float sum = 0.f;
        {   // peaks: centers c = j+1 in [1, NJ]
            int clo = max(1, p - Rp), chi = min(NJ, p + Rp);
            for (int c = clo; c <= chi; ++c)
                sum += s_pk[c - 1 - jb] * s_gp[p - c + 128];
        }
        {   // valleys
            int clo = max(1, p - Rv), chi = min(NJ, p + Rv);
            for (int c = clo; c <= chi; ++c)
                sum += s_vl[c - 1 - jb] * s_gv[p - c + 128];
        }
        vec[p] = sum;

        float mn = sum, mx = sum;
        for (int off = 32; off; off >>= 1) {
            mn = fminf(mn, __shfl_down(mn, off));
            mx = fmaxf(mx, __shfl_down(mx, off));
        }
        if ((tid & 63) == 0) { smn[tid >> 6] = mn; smx[tid >> 6] = mx; }
    }
    __syncthreads();
    if (tid == 0) {
        float mn = fminf(fminf(smn[0], smn[1]), fminf(smn[2], smn[3]));
        float mx = fmaxf(fmaxf(smx[0], smx[1]), fmaxf(smx[2], smx[3]));
        atomicMax(&mm[0], 0x7FFFFFFFu - __float_as_uint(mn));  // min key
        atomicMax(&mm[1], __float_as_uint(mx));                // max key
    }
}

// ---------------------------------------------------------------------------
// Kernel 3: broadcast + normalize. vec (16 KiB) is L1/L2-resident; write-
// bound at ~134 MB. Nontemporal stores skip L2 write-allocate; normalization
// fused (4 FMAs per float4 store, free against write BW).
// ---------------------------------------------------------------------------
__global__ __launch_bounds__(256) void bcast_kernel(
    const float4* __restrict__ vec4,
    const unsigned int* __restrict__ mm,
    f32x4* __restrict__ out4, int total4)
{
    const float mn  = __uint_as_float(0x7FFFFFFFu - mm[0]);
    const float mx  = __uint_as_float(mm[1]);
    const float inv = 1.f / (mx - mn + 1e-6f);

    int idx    = blockIdx.x * blockDim.x + threadIdx.x;
    int stride = gridDim.x * blockDim.x;
    for (int i = idx; i < total4; i += stride) {
        float4 v = vec4[i & 1023];   // N/4 = 1024 (power of two)
        f32x4 o;
        o.x = (v.x - mn) * inv;
        o.y = (v.y - mn) * inv;
        o.z = (v.z - mn) * inv;
        o.w = (v.w - mn) * inv;
        __builtin_nontemporal_store(o, &out4[i]);
    }
}

extern "C" void kernel_launch(void* const* d_in, const int* in_sizes, int n_in,
                              void* d_out, int out_size, void* d_ws, size_t ws_size,
                              hipStream_t stream) {
    const float* x   = (const float*)d_in[0];
    const float* lpw = (const float*)d_in[1];
    const float* lvw = (const float*)d_in[2];

    float* vec = (float*)d_ws;                        // [0..4095], 16B aligned
    unsigned int* mm = (unsigned int*)d_ws + 4096;    // [4096..4097] keys
    unsigned int* partial = (unsigned int*)d_ws + 4352;  // byte 17408, 16B aligned, 2 MB

    // no memset: partial is fully overwritten; mm zeroed by partial_kernel

    dim3 g1(4, G);
    partial_kernel<<<g1, 256, 0, stream>>>(x, partial, mm);
    vec_kernel<<<16, 1024, 0, stream>>>(partial, lpw, lvw, vec, mm);
    bcast_kernel<<<2048, 256, 0, stream>>>((const float4*)vec, mm,
                                           (f32x4*)d_out, out_size / 4);
}